// Round 8
// baseline (907.101 us; speedup 1.0000x reference)
//
#include <hip/hip_runtime.h>
#include <hip/hip_fp16.h>

#define NLV 16
#define TBL (1u << 19)
#define TMASK (TBL - 1u)
#define P1 2654435761u
#define P2 805459861u

typedef float vf2 __attribute__((ext_vector_type(2)));
typedef float vf4 __attribute__((ext_vector_type(4)));
typedef unsigned vu2 __attribute__((ext_vector_type(2)));
typedef unsigned vu4 __attribute__((ext_vector_type(4)));

#if defined(__has_builtin)
#if __has_builtin(__builtin_amdgcn_make_buffer_rsrc) && \
    __has_builtin(__builtin_amdgcn_raw_buffer_load_b64)
#define HAVE_BUF 1
#endif
#endif

__device__ __forceinline__ vf2 h2_to_f2(unsigned bits) {
    union { unsigned u; __half2 h; } c; c.u = bits;
    float2 f = __half22float2(c.h);
    vf2 r; r.x = f.x; r.y = f.y; return r;
}
__device__ __forceinline__ unsigned f2_to_h2(float a, float b) {
    union { __half2 h; unsigned u; } c; c.h = __floats2half2_rn(a, b);
    return c.u;
}

// ---------------------------------------------------------------------------
// Pre-pass A: convert f32 tables ([L][T][2] f32) to packed fp16 (u32/entry).
// ---------------------------------------------------------------------------
__global__ __launch_bounds__(256) void convert_tables(
    const float* __restrict__ tables, unsigned* __restrict__ htab, int total)
{
    int i = blockIdx.x * 256 + threadIdx.x;
    int e0 = i * 2;
    if (e0 >= total) return;
    vf4 v = *(const vf4*)(tables + (size_t)e0 * 2);
    vu2 o; o.x = f2_to_h2(v.x, v.y); o.y = f2_to_h2(v.z, v.w);
    *(vu2*)(htab + e0) = o;
}

// ---------------------------------------------------------------------------
// Pre-pass B: pack u = xyz*0.5+0.5 into aligned float4.
// ---------------------------------------------------------------------------
__global__ __launch_bounds__(256) void pack_u4(
    const float* __restrict__ xyz, vf4* __restrict__ u4, int n)
{
    int p = blockIdx.x * 256 + threadIdx.x;
    if (p >= n) return;
    float x = xyz[(size_t)p * 3 + 0];
    float y = xyz[(size_t)p * 3 + 1];
    float z = xyz[(size_t)p * 3 + 2];
    vf4 r; r.x = x * 0.5f + 0.5f; r.y = y * 0.5f + 0.5f;
    r.z = z * 0.5f + 0.5f; r.w = 0.0f;
    u4[p] = r;
}

// ---------------------------------------------------------------------------
// Pass 1 (templated A/B): identical to R7 except table gathers go through
// raw_buffer_load_b64 with cache-policy AUX.
//   AUX=1 (sc0/GLC): bypass L1, serve from L2  -> tests the L1-fill-wall theory
//   AUX=0          : control, behaves like R7's plain loads
// Launched as two 8-level dispatches (stream-serialized) for per-dispatch
// rocprof attribution.
// ---------------------------------------------------------------------------
template <int AUX>
__global__ __launch_bounds__(256) void ngp_gather_h(
    const vf4* __restrict__ u4,
    const unsigned* __restrict__ htab,
    const int* __restrict__ resolutions,
    unsigned* __restrict__ wsout,
    int n, int nbPerLevel, int Lbase)
{
    int L = Lbase + blockIdx.x / nbPerLevel;
    int chunk = blockIdx.x % nbPerLevel;
    int p0 = chunk * 1024 + (int)threadIdx.x;

    float res = (float)resolutions[L];
    const unsigned* __restrict__ tab = htab + (size_t)L * TBL;
    unsigned* __restrict__ wl = wsout + (size_t)L * n;

#if HAVE_BUF
    __amdgpu_buffer_rsrc_t rs = __builtin_amdgcn_make_buffer_rsrc(
        (void*)tab, (short)0, (int)(TBL * 4u), 0x00020000);
#endif

    unsigned Rj[4][4];
    unsigned e[4], odd[4];
    float wx[4], wyz[4][4];
    bool valid[4];

#pragma unroll
    for (int q = 0; q < 4; ++q) {
        int p = p0 + q * 256;
        valid[q] = (p < n);
        int pp = valid[q] ? p : 0;
        vf4 u = u4[pp];
        float px = u.x * res, py = u.y * res, pz = u.z * res;
        float fx = floorf(px), fy = floorf(py), fz = floorf(pz);
        float wxl = px - fx, wyl = py - fy, wzl = pz - fz;
        unsigned cx = (unsigned)fx, cy = (unsigned)fy, cz = (unsigned)fz;
        e[q] = cx & ~1u;
        odd[q] = cx & 1u;
        unsigned hy0 = cy * P1, hy1 = hy0 + P1;
        unsigned hz0 = cz * P2, hz1 = hz0 + P2;
        Rj[q][0] = hy0 ^ hz0; Rj[q][1] = hy1 ^ hz0;
        Rj[q][2] = hy0 ^ hz1; Rj[q][3] = hy1 ^ hz1;
        float vy = 1.0f - wyl, vz = 1.0f - wzl;
        wx[q] = wxl;
        wyz[q][0] = vy * vz; wyz[q][1] = wyl * vz;
        wyz[q][2] = vy * wzl; wyz[q][3] = wyl * wzl;
    }

    // batch all 16 pair-A loads (full MLP)
    vu2 dA[4][4];
#pragma unroll
    for (int q = 0; q < 4; ++q)
#pragma unroll
        for (int j = 0; j < 4; ++j) {
            unsigned idx = (e[q] ^ Rj[q][j]) & TMASK;
#if HAVE_BUF
            dA[q][j] = __builtin_amdgcn_raw_buffer_load_b64(
                rs, (int)((idx & ~1u) * 4u), 0, AUX);
#else
            dA[q][j] = *(const vu2*)(tab + (idx & ~1u));
#endif
        }

    // masked pair-B loads (only lanes with odd cx need them)
    vu2 dB[4][4];
#pragma unroll
    for (int q = 0; q < 4; ++q) {
#pragma unroll
        for (int j = 0; j < 4; ++j) { dB[q][j].x = 0u; dB[q][j].y = 0u; }
        if (odd[q]) {
#pragma unroll
            for (int j = 0; j < 4; ++j) {
                unsigned idx = ((e[q] + 2u) ^ Rj[q][j]) & TMASK;
#if HAVE_BUF
                dB[q][j] = __builtin_amdgcn_raw_buffer_load_b64(
                    rs, (int)((idx & ~1u) * 4u), 0, AUX);
#else
                dB[q][j] = *(const vu2*)(tab + (idx & ~1u));
#endif
            }
        }
    }

    // consume
#pragma unroll
    for (int q = 0; q < 4; ++q) {
        float vx = 1.0f - wx[q];
        float a0 = 0.0f, a1 = 0.0f;
#pragma unroll
        for (int j = 0; j < 4; ++j) {
            unsigned sA = Rj[q][j] & 1u;          // == idxA&1 == idxB&1 (e even)
            unsigned s0 = sA ^ odd[q];
            unsigned b0 = s0 ? dA[q][j].y : dA[q][j].x;       // x = cx
            unsigned fromA = sA ? dA[q][j].x : dA[q][j].y;    // x = e+1
            unsigned fromB = sA ? dB[q][j].y : dB[q][j].x;    // x = e+2
            unsigned b1 = odd[q] ? fromB : fromA;             // x = cx+1
            vf2 f0 = h2_to_f2(b0);
            vf2 f1 = h2_to_f2(b1);
            float W0 = wyz[q][j] * vx;
            float W1 = wyz[q][j] * wx[q];
            a0 += f0.x * W0; a0 += f1.x * W1;
            a1 += f0.y * W0; a1 += f1.y * W1;
        }
        int p = p0 + q * 256;
        if (valid[q]) wl[p] = f2_to_h2(a0, a1);
    }
}

// ---------------------------------------------------------------------------
// Pass 2: streaming transpose fp16 ws -> f32 output rows. 4 points/thread.
// ---------------------------------------------------------------------------
__global__ __launch_bounds__(256) void ngp_transpose_h(
    const unsigned* __restrict__ ws,
    float* __restrict__ out, int n)
{
    int t = blockIdx.x * 256 + threadIdx.x;
    int p = t * 4;
    if (p >= n) return;

    if (p + 3 < n && (n & 3) == 0) {
        vu4 m[NLV];
#pragma unroll
        for (int L = 0; L < NLV; ++L)
            m[L] = *(const vu4*)(ws + (size_t)L * n + p);
#pragma unroll
        for (int pt = 0; pt < 4; ++pt) {
            vf4* o = (vf4*)(out + (size_t)(p + pt) * (NLV * 2));
#pragma unroll
            for (int i = 0; i < 8; ++i) {
                unsigned ba = pt == 0 ? m[2 * i].x : pt == 1 ? m[2 * i].y
                             : pt == 2 ? m[2 * i].z : m[2 * i].w;
                unsigned bb = pt == 0 ? m[2 * i + 1].x : pt == 1 ? m[2 * i + 1].y
                             : pt == 2 ? m[2 * i + 1].z : m[2 * i + 1].w;
                vf2 ga = h2_to_f2(ba), gb = h2_to_f2(bb);
                vf4 r; r.x = ga.x; r.y = ga.y; r.z = gb.x; r.w = gb.y;
                o[i] = r;
            }
        }
    } else {
        for (int pt = 0; pt < 4 && p + pt < n; ++pt) {
            vf4* o = (vf4*)(out + (size_t)(p + pt) * (NLV * 2));
#pragma unroll
            for (int i = 0; i < 8; ++i) {
                vf2 ga = h2_to_f2(ws[(size_t)(2 * i) * n + p + pt]);
                vf2 gb = h2_to_f2(ws[(size_t)(2 * i + 1) * n + p + pt]);
                vf4 r; r.x = ga.x; r.y = ga.y; r.z = gb.x; r.w = gb.y;
                o[i] = r;
            }
        }
    }
}

// ---------------------------------------------------------------------------
// Fallback: single-pass point-major f32 kernel (ws too small).
// ---------------------------------------------------------------------------
__global__ __launch_bounds__(256) void ngp_encode_kernel(
    const float* __restrict__ xyz,
    const float* __restrict__ tables,
    const int* __restrict__ resolutions,
    float* __restrict__ out,
    int n)
{
    int p = blockIdx.x * blockDim.x + threadIdx.x;
    if (p >= n) return;

    float x = xyz[(size_t)p * 3 + 0];
    float y = xyz[(size_t)p * 3 + 1];
    float z = xyz[(size_t)p * 3 + 2];
    float ux = x * 0.5f + 0.5f;
    float uy = y * 0.5f + 0.5f;
    float uz = z * 0.5f + 0.5f;

    float acc[NLV * 2];

#pragma unroll
    for (int L = 0; L < NLV; ++L) {
        float res = (float)resolutions[L];
        float px = ux * res, py = uy * res, pz = uz * res;
        float fx = floorf(px), fy = floorf(py), fz = floorf(pz);
        float wx = px - fx, wy = py - fy, wz = pz - fz;
        unsigned cx = (unsigned)fx, cy = (unsigned)fy, cz = (unsigned)fz;
        unsigned hx0 = cx, hx1 = cx + 1u;
        unsigned hy0 = cy * P1, hy1 = hy0 + P1;
        unsigned hz0 = cz * P2, hz1 = hz0 + P2;
        const vf2* __restrict__ tab = (const vf2*)tables + (size_t)L * TBL;
        float vx = 1.0f - wx, vy = 1.0f - wy, vz = 1.0f - wz;
        float a0 = 0.0f, a1 = 0.0f;
#pragma unroll
        for (int c = 0; c < 8; ++c) {
            unsigned h = ((c & 1) ? hx1 : hx0) ^
                         ((c & 2) ? hy1 : hy0) ^
                         ((c & 4) ? hz1 : hz0);
            vf2 f = tab[h & TMASK];
            float w = ((c & 1) ? wx : vx) *
                      ((c & 2) ? wy : vy) *
                      ((c & 4) ? wz : vz);
            a0 += f.x * w;
            a1 += f.y * w;
        }
        acc[L * 2 + 0] = a0;
        acc[L * 2 + 1] = a1;
    }

    vf4* o = (vf4*)(out + (size_t)p * (NLV * 2));
#pragma unroll
    for (int i = 0; i < 8; ++i) {
        vf4 r; r.x = acc[i * 4 + 0]; r.y = acc[i * 4 + 1];
        r.z = acc[i * 4 + 2]; r.w = acc[i * 4 + 3];
        o[i] = r;
    }
}

extern "C" void kernel_launch(void* const* d_in, const int* in_sizes, int n_in,
                              void* d_out, int out_size, void* d_ws, size_t ws_size,
                              hipStream_t stream) {
    const float* xyz = (const float*)d_in[0];
    const float* tables = (const float*)d_in[1];
    const int* resolutions = (const int*)d_in[2];
    float* out = (float*)d_out;

    int n = in_sizes[0] / 3;
    const int totalEntries = NLV * (int)TBL;               // 8.39M
    const size_t tabBytes = (size_t)totalEntries * 4;      // 33.5 MB
    const size_t u4Bytes = (size_t)n * sizeof(vf4);        // 33.5 MB
    const size_t wsoutBytes = (size_t)NLV * (size_t)n * 4; // 134 MB

    if (ws_size >= tabBytes + u4Bytes + wsoutBytes) {
        unsigned* htab = (unsigned*)d_ws;
        vf4* u4 = (vf4*)((char*)d_ws + tabBytes);
        unsigned* wsout = (unsigned*)((char*)d_ws + tabBytes + u4Bytes);

        int gridC = (totalEntries / 2 + 255) / 256;
        hipLaunchKernelGGL(convert_tables, dim3(gridC), dim3(256), 0, stream,
                           tables, htab, totalEntries);

        int gridU = (n + 255) / 256;
        hipLaunchKernelGGL(pack_u4, dim3(gridU), dim3(256), 0, stream,
                           xyz, u4, n);

        int nbPerLevel = (n + 1023) / 1024;
        int grid1 = 8 * nbPerLevel;
        // A: levels 0-7 with sc0 (bypass L1) table gathers
        hipLaunchKernelGGL((ngp_gather_h<1>), dim3(grid1), dim3(256), 0, stream,
                           u4, htab, resolutions, wsout, n, nbPerLevel, 0);
        // B: levels 8-15 control (plain cache policy)
        hipLaunchKernelGGL((ngp_gather_h<0>), dim3(grid1), dim3(256), 0, stream,
                           u4, htab, resolutions, wsout, n, nbPerLevel, 8);

        int grid2 = ((n + 3) / 4 + 255) / 256;
        hipLaunchKernelGGL(ngp_transpose_h, dim3(grid2), dim3(256), 0, stream,
                           wsout, out, n);
    } else {
        int grid = (n + 255) / 256;
        hipLaunchKernelGGL(ngp_encode_kernel, dim3(grid), dim3(256), 0, stream,
                           xyz, tables, resolutions, out, n);
    }
}

// Round 9
// 884.188 us; speedup vs baseline: 1.0259x; 1.0259x over previous
//
#include <hip/hip_runtime.h>
#include <hip/hip_fp16.h>

#define NLV 16
#define TBL (1u << 19)
#define TMASK (TBL - 1u)
#define P1 2654435761u
#define P2 805459861u
#define NBIN (1 << 18)   // 64^3 Morton bins

typedef float vf2 __attribute__((ext_vector_type(2)));
typedef float vf4 __attribute__((ext_vector_type(4)));
typedef unsigned vu2 __attribute__((ext_vector_type(2)));

__device__ __forceinline__ vf2 h2_to_f2(unsigned bits) {
    union { unsigned u; __half2 h; } c; c.u = bits;
    float2 f = __half22float2(c.h);
    vf2 r; r.x = f.x; r.y = f.y; return r;
}
__device__ __forceinline__ unsigned f2_to_h2(float a, float b) {
    union { __half2 h; unsigned u; } c; c.h = __floats2half2_rn(a, b);
    return c.u;
}

// spread 6 bits to every 3rd position (3D Morton)
__device__ __forceinline__ unsigned mort6(unsigned v) {
    v &= 63u;
    v = (v | (v << 16)) & 0x030000FFu;
    v = (v | (v << 8))  & 0x0300F00Fu;
    v = (v | (v << 4))  & 0x030C30C3u;
    v = (v | (v << 2))  & 0x09249249u;
    return v;
}

__device__ __forceinline__ unsigned bin_of(float ux, float uy, float uz) {
    unsigned bx = min(63u, (unsigned)(ux * 64.0f));
    unsigned by = min(63u, (unsigned)(uy * 64.0f));
    unsigned bz = min(63u, (unsigned)(uz * 64.0f));
    return mort6(bx) | (mort6(by) << 1) | (mort6(bz) << 2);
}

// ---------------------------------------------------------------------------
// Pre-pass A: f32 tables -> packed fp16 (u32/entry).
// ---------------------------------------------------------------------------
__global__ __launch_bounds__(256) void convert_tables(
    const float* __restrict__ tables, unsigned* __restrict__ htab, int total)
{
    int i = blockIdx.x * 256 + threadIdx.x;
    int e0 = i * 2;
    if (e0 >= total) return;
    vf4 v = *(const vf4*)(tables + (size_t)e0 * 2);
    vu2 o; o.x = f2_to_h2(v.x, v.y); o.y = f2_to_h2(v.z, v.w);
    *(vu2*)(htab + e0) = o;
}

// ---------------------------------------------------------------------------
// Sort step 1: histogram of Morton bins.
// ---------------------------------------------------------------------------
__global__ __launch_bounds__(256) void hist_kernel(
    const float* __restrict__ xyz, unsigned* __restrict__ hist, int n)
{
    int p = blockIdx.x * 256 + threadIdx.x;
    if (p >= n) return;
    float ux = xyz[(size_t)p * 3 + 0] * 0.5f + 0.5f;
    float uy = xyz[(size_t)p * 3 + 1] * 0.5f + 0.5f;
    float uz = xyz[(size_t)p * 3 + 2] * 0.5f + 0.5f;
    atomicAdd(&hist[bin_of(ux, uy, uz)], 1u);
}

// ---------------------------------------------------------------------------
// Sort step 2: in-place exclusive scan of NBIN counters (single block).
// ---------------------------------------------------------------------------
__global__ __launch_bounds__(1024) void scan_bins(unsigned* __restrict__ hist)
{
    __shared__ unsigned part[1024];
    int t = threadIdx.x;
    int base = t * (NBIN / 1024);
    unsigned s = 0;
    for (int j = 0; j < NBIN / 1024; ++j) s += hist[base + j];
    part[t] = s;
    __syncthreads();
    for (int off = 1; off < 1024; off <<= 1) {
        unsigned v = (t >= off) ? part[t - off] : 0u;
        __syncthreads();
        part[t] += v;
        __syncthreads();
    }
    unsigned run = (t == 0) ? 0u : part[t - 1];
    for (int j = 0; j < NBIN / 1024; ++j) {
        unsigned tmp = hist[base + j];
        hist[base + j] = run;
        run += tmp;
    }
}

// ---------------------------------------------------------------------------
// Sort step 3: scatter points to sorted positions; store u4 and orig index.
// (Bin-internal order is race-dependent, but the final output is written
//  per original index -> deterministic d_out.)
// ---------------------------------------------------------------------------
__global__ __launch_bounds__(256) void scatter_kernel(
    const float* __restrict__ xyz, unsigned* __restrict__ start,
    vf4* __restrict__ u4s, int* __restrict__ orig, int n)
{
    int p = blockIdx.x * 256 + threadIdx.x;
    if (p >= n) return;
    float ux = xyz[(size_t)p * 3 + 0] * 0.5f + 0.5f;
    float uy = xyz[(size_t)p * 3 + 1] * 0.5f + 0.5f;
    float uz = xyz[(size_t)p * 3 + 2] * 0.5f + 0.5f;
    unsigned pos = atomicAdd(&start[bin_of(ux, uy, uz)], 1u);
    orig[pos] = p;
    vf4 r; r.x = ux; r.y = uy; r.z = uz; r.w = 0.0f;
    u4s[pos] = r;
}

// ---------------------------------------------------------------------------
// Pass 1: level-major gather over SORTED points. Plain 8 x u32 fp16-table
// gathers per point-level (no pairing - R7 showed its VALU cost eats the
// request savings), 4 pts/thread, all 32 loads batched for MLP.
// Sorted order -> wave-local spatial coherence -> shared table lines at
// low/mid levels (the line-touch wall identified R2-R8).
// ---------------------------------------------------------------------------
__global__ __launch_bounds__(256) void ngp_gather_s(
    const vf4* __restrict__ u4s,
    const unsigned* __restrict__ htab,
    const int* __restrict__ resolutions,
    unsigned* __restrict__ wsout,
    int n, int nbPerLevel)
{
    int L = blockIdx.x / nbPerLevel;
    int chunk = blockIdx.x % nbPerLevel;
    int p0 = chunk * 1024 + (int)threadIdx.x;

    float res = (float)resolutions[L];
    const unsigned* __restrict__ tab = htab + (size_t)L * TBL;
    unsigned* __restrict__ wl = wsout + (size_t)L * n;

    unsigned idx[4][8];
    float wx[4], wyz[4][4];
    bool valid[4];

#pragma unroll
    for (int q = 0; q < 4; ++q) {
        int p = p0 + q * 256;
        valid[q] = (p < n);
        int pp = valid[q] ? p : 0;
        vf4 u = u4s[pp];
        float px = u.x * res, py = u.y * res, pz = u.z * res;
        float fx = floorf(px), fy = floorf(py), fz = floorf(pz);
        float wxl = px - fx, wyl = py - fy, wzl = pz - fz;
        unsigned cx = (unsigned)fx, cy = (unsigned)fy, cz = (unsigned)fz;
        unsigned hx0 = cx, hx1 = cx + 1u;
        unsigned hy0 = cy * P1, hy1 = hy0 + P1;
        unsigned hz0 = cz * P2, hz1 = hz0 + P2;
#pragma unroll
        for (int c = 0; c < 8; ++c)
            idx[q][c] = ((((c & 1) ? hx1 : hx0) ^
                          ((c & 2) ? hy1 : hy0) ^
                          ((c & 4) ? hz1 : hz0)) & TMASK);
        float vy = 1.0f - wyl, vz = 1.0f - wzl;
        wx[q] = wxl;
        wyz[q][0] = vy * vz;  wyz[q][1] = wyl * vz;
        wyz[q][2] = vy * wzl; wyz[q][3] = wyl * wzl;
    }

    unsigned d[4][8];
#pragma unroll
    for (int q = 0; q < 4; ++q)
#pragma unroll
        for (int c = 0; c < 8; ++c)
            d[q][c] = tab[idx[q][c]];

#pragma unroll
    for (int q = 0; q < 4; ++q) {
        float vx = 1.0f - wx[q];
        float a0 = 0.0f, a1 = 0.0f;
#pragma unroll
        for (int c = 0; c < 8; ++c) {
            float w = wyz[q][c >> 1] * ((c & 1) ? wx[q] : vx);
            vf2 f = h2_to_f2(d[q][c]);
            a0 += f.x * w;
            a1 += f.y * w;
        }
        int p = p0 + q * 256;
        if (valid[q]) wl[p] = f2_to_h2(a0, a1);
    }
}

// ---------------------------------------------------------------------------
// Pass 2: coalesced ws reads (sorted order), scatter full 128B output rows
// to the original point index. Full-line writes -> L2 write-combines.
// ---------------------------------------------------------------------------
__global__ __launch_bounds__(256) void ngp_finalize_s(
    const unsigned* __restrict__ ws, const int* __restrict__ orig,
    float* __restrict__ out, int n)
{
    int i = blockIdx.x * 256 + threadIdx.x;
    if (i >= n) return;
    int op = orig[i];
    vf4* o = (vf4*)(out + (size_t)op * (NLV * 2));
#pragma unroll
    for (int j = 0; j < 8; ++j) {
        vf2 ga = h2_to_f2(ws[(size_t)(2 * j) * n + i]);
        vf2 gb = h2_to_f2(ws[(size_t)(2 * j + 1) * n + i]);
        vf4 r; r.x = ga.x; r.y = ga.y; r.z = gb.x; r.w = gb.y;
        o[j] = r;
    }
}

// ---------------------------------------------------------------------------
// Fallback: single-pass point-major f32 kernel (ws too small).
// ---------------------------------------------------------------------------
__global__ __launch_bounds__(256) void ngp_encode_kernel(
    const float* __restrict__ xyz,
    const float* __restrict__ tables,
    const int* __restrict__ resolutions,
    float* __restrict__ out,
    int n)
{
    int p = blockIdx.x * blockDim.x + threadIdx.x;
    if (p >= n) return;

    float x = xyz[(size_t)p * 3 + 0];
    float y = xyz[(size_t)p * 3 + 1];
    float z = xyz[(size_t)p * 3 + 2];
    float ux = x * 0.5f + 0.5f;
    float uy = y * 0.5f + 0.5f;
    float uz = z * 0.5f + 0.5f;

    float acc[NLV * 2];

#pragma unroll
    for (int L = 0; L < NLV; ++L) {
        float res = (float)resolutions[L];
        float px = ux * res, py = uy * res, pz = uz * res;
        float fx = floorf(px), fy = floorf(py), fz = floorf(pz);
        float wx = px - fx, wy = py - fy, wz = pz - fz;
        unsigned cx = (unsigned)fx, cy = (unsigned)fy, cz = (unsigned)fz;
        unsigned hx0 = cx, hx1 = cx + 1u;
        unsigned hy0 = cy * P1, hy1 = hy0 + P1;
        unsigned hz0 = cz * P2, hz1 = hz0 + P2;
        const vf2* __restrict__ tab = (const vf2*)tables + (size_t)L * TBL;
        float vx = 1.0f - wx, vy = 1.0f - wy, vz = 1.0f - wz;
        float a0 = 0.0f, a1 = 0.0f;
#pragma unroll
        for (int c = 0; c < 8; ++c) {
            unsigned h = ((c & 1) ? hx1 : hx0) ^
                         ((c & 2) ? hy1 : hy0) ^
                         ((c & 4) ? hz1 : hz0);
            vf2 f = tab[h & TMASK];
            float w = ((c & 1) ? wx : vx) *
                      ((c & 2) ? wy : vy) *
                      ((c & 4) ? wz : vz);
            a0 += f.x * w;
            a1 += f.y * w;
        }
        acc[L * 2 + 0] = a0;
        acc[L * 2 + 1] = a1;
    }

    vf4* o = (vf4*)(out + (size_t)p * (NLV * 2));
#pragma unroll
    for (int i = 0; i < 8; ++i) {
        vf4 r; r.x = acc[i * 4 + 0]; r.y = acc[i * 4 + 1];
        r.z = acc[i * 4 + 2]; r.w = acc[i * 4 + 3];
        o[i] = r;
    }
}

extern "C" void kernel_launch(void* const* d_in, const int* in_sizes, int n_in,
                              void* d_out, int out_size, void* d_ws, size_t ws_size,
                              hipStream_t stream) {
    const float* xyz = (const float*)d_in[0];
    const float* tables = (const float*)d_in[1];
    const int* resolutions = (const int*)d_in[2];
    float* out = (float*)d_out;

    int n = in_sizes[0] / 3;
    const int totalEntries = NLV * (int)TBL;

    const size_t tabBytes  = (size_t)totalEntries * 4;      // 33.5 MB
    const size_t u4Bytes   = (size_t)n * sizeof(vf4);       // 33.5 MB
    const size_t origBytes = (size_t)n * 4;                 // 8.4 MB
    const size_t histBytes = (size_t)NBIN * 4;              // 1 MB
    const size_t wsoutBytes = (size_t)NLV * (size_t)n * 4;  // 134 MB
    const size_t need = tabBytes + u4Bytes + origBytes + histBytes + wsoutBytes;

    if (ws_size >= need) {
        char* base = (char*)d_ws;
        unsigned* htab  = (unsigned*)base;                       base += tabBytes;
        vf4*      u4s   = (vf4*)base;                            base += u4Bytes;
        int*      orig  = (int*)base;                            base += origBytes;
        unsigned* hist  = (unsigned*)base;                       base += histBytes;
        unsigned* wsout = (unsigned*)base;

        hipMemsetAsync(hist, 0, histBytes, stream);

        int gridC = (totalEntries / 2 + 255) / 256;
        hipLaunchKernelGGL(convert_tables, dim3(gridC), dim3(256), 0, stream,
                           tables, htab, totalEntries);

        int gridP = (n + 255) / 256;
        hipLaunchKernelGGL(hist_kernel, dim3(gridP), dim3(256), 0, stream,
                           xyz, hist, n);
        hipLaunchKernelGGL(scan_bins, dim3(1), dim3(1024), 0, stream, hist);
        hipLaunchKernelGGL(scatter_kernel, dim3(gridP), dim3(256), 0, stream,
                           xyz, hist, u4s, orig, n);

        int nbPerLevel = (n + 1023) / 1024;
        int grid1 = NLV * nbPerLevel;
        hipLaunchKernelGGL(ngp_gather_s, dim3(grid1), dim3(256), 0, stream,
                           u4s, htab, resolutions, wsout, n, nbPerLevel);

        hipLaunchKernelGGL(ngp_finalize_s, dim3(gridP), dim3(256), 0, stream,
                           wsout, orig, out, n);
    } else {
        int grid = (n + 255) / 256;
        hipLaunchKernelGGL(ngp_encode_kernel, dim3(grid), dim3(256), 0, stream,
                           xyz, tables, resolutions, out, n);
    }
}

// Round 10
// 807.799 us; speedup vs baseline: 1.1229x; 1.0946x over previous
//
#include <hip/hip_runtime.h>
#include <hip/hip_fp16.h>

#define NLV 16
#define TBL (1u << 19)
#define TMASK (TBL - 1u)
#define P1 2654435761u
#define P2 805459861u
#define NBIN (1 << 15)   // 32^3 Morton bins (R10: was 64^3; scan 8x cheaper,
                         // wave-level spatial extent identical)

typedef float vf2 __attribute__((ext_vector_type(2)));
typedef float vf4 __attribute__((ext_vector_type(4)));
typedef unsigned vu2 __attribute__((ext_vector_type(2)));
typedef unsigned vu4 __attribute__((ext_vector_type(4)));
typedef int vi4 __attribute__((ext_vector_type(4)));

__device__ __forceinline__ vf2 h2_to_f2(unsigned bits) {
    union { unsigned u; __half2 h; } c; c.u = bits;
    float2 f = __half22float2(c.h);
    vf2 r; r.x = f.x; r.y = f.y; return r;
}
__device__ __forceinline__ unsigned f2_to_h2(float a, float b) {
    union { __half2 h; unsigned u; } c; c.h = __floats2half2_rn(a, b);
    return c.u;
}

// spread bits to every 3rd position (3D Morton, 5-bit coords)
__device__ __forceinline__ unsigned mort5(unsigned v) {
    v &= 31u;
    v = (v | (v << 16)) & 0x030000FFu;
    v = (v | (v << 8))  & 0x0300F00Fu;
    v = (v | (v << 4))  & 0x030C30C3u;
    v = (v | (v << 2))  & 0x09249249u;
    return v;
}

__device__ __forceinline__ unsigned bin_of(float ux, float uy, float uz) {
    unsigned bx = min(31u, (unsigned)(ux * 32.0f));
    unsigned by = min(31u, (unsigned)(uy * 32.0f));
    unsigned bz = min(31u, (unsigned)(uz * 32.0f));
    return mort5(bx) | (mort5(by) << 1) | (mort5(bz) << 2);
}

// ---------------------------------------------------------------------------
// Pre-pass A: f32 tables -> packed fp16 (u32/entry).
// ---------------------------------------------------------------------------
__global__ __launch_bounds__(256) void convert_tables(
    const float* __restrict__ tables, unsigned* __restrict__ htab, int total)
{
    int i = blockIdx.x * 256 + threadIdx.x;
    int e0 = i * 2;
    if (e0 >= total) return;
    vf4 v = *(const vf4*)(tables + (size_t)e0 * 2);
    vu2 o; o.x = f2_to_h2(v.x, v.y); o.y = f2_to_h2(v.z, v.w);
    *(vu2*)(htab + e0) = o;
}

// ---------------------------------------------------------------------------
// Sort step 1: histogram of Morton bins.
// ---------------------------------------------------------------------------
__global__ __launch_bounds__(256) void hist_kernel(
    const float* __restrict__ xyz, unsigned* __restrict__ hist, int n)
{
    int p = blockIdx.x * 256 + threadIdx.x;
    if (p >= n) return;
    float ux = xyz[(size_t)p * 3 + 0] * 0.5f + 0.5f;
    float uy = xyz[(size_t)p * 3 + 1] * 0.5f + 0.5f;
    float uz = xyz[(size_t)p * 3 + 2] * 0.5f + 0.5f;
    atomicAdd(&hist[bin_of(ux, uy, uz)], 1u);
}

// ---------------------------------------------------------------------------
// Sort step 2: in-place exclusive scan of NBIN counters (single block,
// 32 elems/thread at NBIN=32K).
// ---------------------------------------------------------------------------
__global__ __launch_bounds__(1024) void scan_bins(unsigned* __restrict__ hist)
{
    __shared__ unsigned part[1024];
    int t = threadIdx.x;
    int base = t * (NBIN / 1024);
    unsigned s = 0;
    for (int j = 0; j < NBIN / 1024; ++j) s += hist[base + j];
    part[t] = s;
    __syncthreads();
    for (int off = 1; off < 1024; off <<= 1) {
        unsigned v = (t >= off) ? part[t - off] : 0u;
        __syncthreads();
        part[t] += v;
        __syncthreads();
    }
    unsigned run = (t == 0) ? 0u : part[t - 1];
    for (int j = 0; j < NBIN / 1024; ++j) {
        unsigned tmp = hist[base + j];
        hist[base + j] = run;
        run += tmp;
    }
}

// ---------------------------------------------------------------------------
// Sort step 3: scatter points to sorted positions; store u4 and orig index.
// (Bin-internal order is race-dependent, but output is written per original
//  index from order-independent values -> deterministic d_out.)
// ---------------------------------------------------------------------------
__global__ __launch_bounds__(256) void scatter_kernel(
    const float* __restrict__ xyz, unsigned* __restrict__ start,
    vf4* __restrict__ u4s, int* __restrict__ orig, int n)
{
    int p = blockIdx.x * 256 + threadIdx.x;
    if (p >= n) return;
    float ux = xyz[(size_t)p * 3 + 0] * 0.5f + 0.5f;
    float uy = xyz[(size_t)p * 3 + 1] * 0.5f + 0.5f;
    float uz = xyz[(size_t)p * 3 + 2] * 0.5f + 0.5f;
    unsigned pos = atomicAdd(&start[bin_of(ux, uy, uz)], 1u);
    orig[pos] = p;
    vf4 r; r.x = ux; r.y = uy; r.z = uz; r.w = 0.0f;
    u4s[pos] = r;
}

// ---------------------------------------------------------------------------
// Pass 1 (unchanged from R9's 388us config): level-major gather over SORTED
// points, fp16 tables, 4 pts/thread, all 32 loads batched for MLP.
// ---------------------------------------------------------------------------
__global__ __launch_bounds__(256) void ngp_gather_s(
    const vf4* __restrict__ u4s,
    const unsigned* __restrict__ htab,
    const int* __restrict__ resolutions,
    unsigned* __restrict__ wsout,
    int n, int nbPerLevel)
{
    int L = blockIdx.x / nbPerLevel;
    int chunk = blockIdx.x % nbPerLevel;
    int p0 = chunk * 1024 + (int)threadIdx.x;

    float res = (float)resolutions[L];
    const unsigned* __restrict__ tab = htab + (size_t)L * TBL;
    unsigned* __restrict__ wl = wsout + (size_t)L * n;

    unsigned idx[4][8];
    float wx[4], wyz[4][4];
    bool valid[4];

#pragma unroll
    for (int q = 0; q < 4; ++q) {
        int p = p0 + q * 256;
        valid[q] = (p < n);
        int pp = valid[q] ? p : 0;
        vf4 u = u4s[pp];
        float px = u.x * res, py = u.y * res, pz = u.z * res;
        float fx = floorf(px), fy = floorf(py), fz = floorf(pz);
        float wxl = px - fx, wyl = py - fy, wzl = pz - fz;
        unsigned cx = (unsigned)fx, cy = (unsigned)fy, cz = (unsigned)fz;
        unsigned hx0 = cx, hx1 = cx + 1u;
        unsigned hy0 = cy * P1, hy1 = hy0 + P1;
        unsigned hz0 = cz * P2, hz1 = hz0 + P2;
#pragma unroll
        for (int c = 0; c < 8; ++c)
            idx[q][c] = ((((c & 1) ? hx1 : hx0) ^
                          ((c & 2) ? hy1 : hy0) ^
                          ((c & 4) ? hz1 : hz0)) & TMASK);
        float vy = 1.0f - wyl, vz = 1.0f - wzl;
        wx[q] = wxl;
        wyz[q][0] = vy * vz;  wyz[q][1] = wyl * vz;
        wyz[q][2] = vy * wzl; wyz[q][3] = wyl * wzl;
    }

    unsigned d[4][8];
#pragma unroll
    for (int q = 0; q < 4; ++q)
#pragma unroll
        for (int c = 0; c < 8; ++c)
            d[q][c] = tab[idx[q][c]];

#pragma unroll
    for (int q = 0; q < 4; ++q) {
        float vx = 1.0f - wx[q];
        float a0 = 0.0f, a1 = 0.0f;
#pragma unroll
        for (int c = 0; c < 8; ++c) {
            float w = wyz[q][c >> 1] * ((c & 1) ? wx[q] : vx);
            vf2 f = h2_to_f2(d[q][c]);
            a0 += f.x * w;
            a1 += f.y * w;
        }
        int p = p0 + q * 256;
        if (valid[q]) wl[p] = f2_to_h2(a0, a1);
    }
}

// ---------------------------------------------------------------------------
// Pass 2 (R10: vectorized 4 pts/thread): 16 x vu4 coalesced stream reads,
// orig as int4, scatter 4 full 128B output rows (2 full 64B lines each).
// ---------------------------------------------------------------------------
__global__ __launch_bounds__(256) void ngp_finalize_s(
    const unsigned* __restrict__ ws, const int* __restrict__ orig,
    float* __restrict__ out, int n)
{
    int t = blockIdx.x * 256 + threadIdx.x;
    int i = t * 4;
    if (i >= n) return;

    if (i + 3 < n && (n & 3) == 0) {
        vu4 m[NLV];
#pragma unroll
        for (int L = 0; L < NLV; ++L)
            m[L] = *(const vu4*)(ws + (size_t)L * n + i);
        vi4 og = *(const vi4*)(orig + i);
#pragma unroll
        for (int pt = 0; pt < 4; ++pt) {
            int op = pt == 0 ? og.x : pt == 1 ? og.y : pt == 2 ? og.z : og.w;
            vf4* o = (vf4*)(out + (size_t)op * (NLV * 2));
#pragma unroll
            for (int j = 0; j < 8; ++j) {
                unsigned ba = pt == 0 ? m[2 * j].x : pt == 1 ? m[2 * j].y
                             : pt == 2 ? m[2 * j].z : m[2 * j].w;
                unsigned bb = pt == 0 ? m[2 * j + 1].x : pt == 1 ? m[2 * j + 1].y
                             : pt == 2 ? m[2 * j + 1].z : m[2 * j + 1].w;
                vf2 ga = h2_to_f2(ba), gb = h2_to_f2(bb);
                vf4 r; r.x = ga.x; r.y = ga.y; r.z = gb.x; r.w = gb.y;
                o[j] = r;
            }
        }
    } else {
        for (int pt = 0; pt < 4 && i + pt < n; ++pt) {
            int op = orig[i + pt];
            vf4* o = (vf4*)(out + (size_t)op * (NLV * 2));
#pragma unroll
            for (int j = 0; j < 8; ++j) {
                vf2 ga = h2_to_f2(ws[(size_t)(2 * j) * n + i + pt]);
                vf2 gb = h2_to_f2(ws[(size_t)(2 * j + 1) * n + i + pt]);
                vf4 r; r.x = ga.x; r.y = ga.y; r.z = gb.x; r.w = gb.y;
                o[j] = r;
            }
        }
    }
}

// ---------------------------------------------------------------------------
// Fallback: single-pass point-major f32 kernel (ws too small).
// ---------------------------------------------------------------------------
__global__ __launch_bounds__(256) void ngp_encode_kernel(
    const float* __restrict__ xyz,
    const float* __restrict__ tables,
    const int* __restrict__ resolutions,
    float* __restrict__ out,
    int n)
{
    int p = blockIdx.x * blockDim.x + threadIdx.x;
    if (p >= n) return;

    float x = xyz[(size_t)p * 3 + 0];
    float y = xyz[(size_t)p * 3 + 1];
    float z = xyz[(size_t)p * 3 + 2];
    float ux = x * 0.5f + 0.5f;
    float uy = y * 0.5f + 0.5f;
    float uz = z * 0.5f + 0.5f;

    float acc[NLV * 2];

#pragma unroll
    for (int L = 0; L < NLV; ++L) {
        float res = (float)resolutions[L];
        float px = ux * res, py = uy * res, pz = uz * res;
        float fx = floorf(px), fy = floorf(py), fz = floorf(pz);
        float wx = px - fx, wy = py - fy, wz = pz - fz;
        unsigned cx = (unsigned)fx, cy = (unsigned)fy, cz = (unsigned)fz;
        unsigned hx0 = cx, hx1 = cx + 1u;
        unsigned hy0 = cy * P1, hy1 = hy0 + P1;
        unsigned hz0 = cz * P2, hz1 = hz0 + P2;
        const vf2* __restrict__ tab = (const vf2*)tables + (size_t)L * TBL;
        float vx = 1.0f - wx, vy = 1.0f - wy, vz = 1.0f - wz;
        float a0 = 0.0f, a1 = 0.0f;
#pragma unroll
        for (int c = 0; c < 8; ++c) {
            unsigned h = ((c & 1) ? hx1 : hx0) ^
                         ((c & 2) ? hy1 : hy0) ^
                         ((c & 4) ? hz1 : hz0);
            vf2 f = tab[h & TMASK];
            float w = ((c & 1) ? wx : vx) *
                      ((c & 2) ? wy : vy) *
                      ((c & 4) ? wz : vz);
            a0 += f.x * w;
            a1 += f.y * w;
        }
        acc[L * 2 + 0] = a0;
        acc[L * 2 + 1] = a1;
    }

    vf4* o = (vf4*)(out + (size_t)p * (NLV * 2));
#pragma unroll
    for (int i = 0; i < 8; ++i) {
        vf4 r; r.x = acc[i * 4 + 0]; r.y = acc[i * 4 + 1];
        r.z = acc[i * 4 + 2]; r.w = acc[i * 4 + 3];
        o[i] = r;
    }
}

extern "C" void kernel_launch(void* const* d_in, const int* in_sizes, int n_in,
                              void* d_out, int out_size, void* d_ws, size_t ws_size,
                              hipStream_t stream) {
    const float* xyz = (const float*)d_in[0];
    const float* tables = (const float*)d_in[1];
    const int* resolutions = (const int*)d_in[2];
    float* out = (float*)d_out;

    int n = in_sizes[0] / 3;
    const int totalEntries = NLV * (int)TBL;

    const size_t tabBytes  = (size_t)totalEntries * 4;      // 33.5 MB
    const size_t u4Bytes   = (size_t)n * sizeof(vf4);       // 33.5 MB
    const size_t origBytes = (size_t)n * 4;                 // 8.4 MB
    const size_t histBytes = (size_t)NBIN * 4;              // 128 KB
    const size_t wsoutBytes = (size_t)NLV * (size_t)n * 4;  // 134 MB
    const size_t need = tabBytes + u4Bytes + origBytes + histBytes + wsoutBytes;

    if (ws_size >= need) {
        char* base = (char*)d_ws;
        unsigned* htab  = (unsigned*)base;                       base += tabBytes;
        vf4*      u4s   = (vf4*)base;                            base += u4Bytes;
        int*      orig  = (int*)base;                            base += origBytes;
        unsigned* hist  = (unsigned*)base;                       base += histBytes;
        unsigned* wsout = (unsigned*)base;

        hipMemsetAsync(hist, 0, histBytes, stream);

        int gridC = (totalEntries / 2 + 255) / 256;
        hipLaunchKernelGGL(convert_tables, dim3(gridC), dim3(256), 0, stream,
                           tables, htab, totalEntries);

        int gridP = (n + 255) / 256;
        hipLaunchKernelGGL(hist_kernel, dim3(gridP), dim3(256), 0, stream,
                           xyz, hist, n);
        hipLaunchKernelGGL(scan_bins, dim3(1), dim3(1024), 0, stream, hist);
        hipLaunchKernelGGL(scatter_kernel, dim3(gridP), dim3(256), 0, stream,
                           xyz, hist, u4s, orig, n);

        int nbPerLevel = (n + 1023) / 1024;
        int grid1 = NLV * nbPerLevel;
        hipLaunchKernelGGL(ngp_gather_s, dim3(grid1), dim3(256), 0, stream,
                           u4s, htab, resolutions, wsout, n, nbPerLevel);

        int gridF = ((n + 3) / 4 + 255) / 256;
        hipLaunchKernelGGL(ngp_finalize_s, dim3(gridF), dim3(256), 0, stream,
                           wsout, orig, out, n);
    } else {
        int grid = (n + 255) / 256;
        hipLaunchKernelGGL(ngp_encode_kernel, dim3(grid), dim3(256), 0, stream,
                           xyz, tables, resolutions, out, n);
    }
}